// Round 13
// baseline (64.330 us; speedup 1.0000x reference)
//
#include <hip/hip_runtime.h>
#include <hip/hip_bf16.h>
#include <math.h>

#define B_  128
#define N_  16
#define T_  200
#define H_  64
#define J1  80
#define J2  40
#define NTILE 13
#define NEGV -4294967295.0f   // -2^32 + 1

typedef __attribute__((ext_vector_type(8))) short bf16x8;
typedef __attribute__((ext_vector_type(4))) float f32x4;

__device__ __forceinline__ float sigmoidf_(float x) {
    return 1.0f / (1.0f + __expf(-x));
}
// branch-free RNE f32->bf16 (finite inputs only)
__device__ __forceinline__ short f2b(float x) {
    unsigned u = __float_as_uint(x);
    return (short)((u + 0x7FFF + ((u >> 16) & 1)) >> 16);
}
__device__ __forceinline__ unsigned pack2(float a, float b) {
    return (unsigned)(unsigned short)f2b(a) | ((unsigned)(unsigned short)f2b(b) << 16);
}
// HW packed convert: dst = {lo16: bf16(a), hi16: bf16(b)} — one VALU op
__device__ __forceinline__ unsigned cvtpk(float a, float b) {
    unsigned r;
    asm("v_cvt_pk_bf16_f32 %0, %1, %2" : "=v"(r) : "v"(a), "v"(b));
    return r;
}
// kq word: in-register bf16 extract + mul + cvt_pk = 5 VALU
__device__ __forceinline__ unsigned kqword(unsigned w, float ql, float qh) {
    float lo = __uint_as_float(w << 16) * ql;
    float hi = __uint_as_float(w & 0xffff0000u) * qh;
    return cvtpk(lo, hi);
}

// ---- prep: ONE dispatch, 5 ranges (verified R12) ------------------------
#define P_QW 160
#define P_WB 20
#define P_KB 416
#define P_W2 9
#define P_PB 1
__global__ void prep(const float* __restrict__ queries,
                     const float* __restrict__ keys,
                     const float* __restrict__ W1,
                     const float* __restrict__ b1,
                     const float* __restrict__ W2,
                     const float* __restrict__ b2,
                     const float* __restrict__ W3,
                     float* __restrict__ QW,
                     unsigned* __restrict__ WBFu,
                     bf16x8* __restrict__ kbf0, bf16x8* __restrict__ kbf1,
                     unsigned* __restrict__ W2F,
                     float* __restrict__ b2p, float* __restrict__ W3p) {
    const int blk = blockIdx.x, tid = threadIdx.x;
    if (blk < P_QW) {
        int idx = blk * 256 + tid;                 // (bn, j/4), exact
        int bn = idx / 20, j = (idx % 20) * 4;
        float4 acc = *(const float4*)(b1 + j);
        const float* qp = queries + bn * H_;
        for (int h = 0; h < H_; ++h) {
            float qh = qp[h];
            float4 wa = *(const float4*)(W1 + h * J1 + j);
            float4 wc = *(const float4*)(W1 + (128 + h) * J1 + j);
            acc.x = fmaf(qh, wa.x + wc.x, acc.x);
            acc.y = fmaf(qh, wa.y + wc.y, acc.y);
            acc.z = fmaf(qh, wa.z + wc.z, acc.z);
            acc.w = fmaf(qh, wa.w + wc.w, acc.w);
        }
        *(float4*)(QW + bn * J1 + j) = acc;
    } else if (blk < P_QW + P_WB) {
        int idx = (blk - P_QW) * 256 + tid;        // = fi*256 + l*4 + rp, exact
        int rp = idx & 3, l = (idx >> 2) & 63, fi = idx >> 8;
        int j  = (fi % 5) * 16 + (l & 15);
        int R  = (fi / 5) * 32 + 8 * (l >> 4) + 2 * rp;
        float a, b;
        if (R < 64) {
            a = W1[(192 + R) * J1 + j];
            b = W1[(193 + R) * J1 + j];
        } else {
            int r2 = R - 64;
            a = W1[(64 + r2) * J1 + j] - W1[(128 + r2) * J1 + j];
            b = W1[(65 + r2) * J1 + j] - W1[(129 + r2) * J1 + j];
        }
        WBFu[idx] = pack2(a, b);
    } else if (blk < P_QW + P_WB + P_KB) {
        int idx = (blk - P_QW - P_WB) * 256 + tid; // (b*13+mt)*64+l, exact
        int l  = idx & 63, bm = idx >> 6;
        int mt = bm % NTILE, b = bm / NTILE;
        int t  = mt * 16 + (l & 15); if (t > T_ - 1) t = T_ - 1;
        int rg = l >> 4;
        const float* kr = keys + ((size_t)(b * T_ + t)) * H_ + 8 * rg;
        float4 a0 = *(const float4*)(kr);
        float4 a1 = *(const float4*)(kr + 4);
        float4 a2 = *(const float4*)(kr + 32);
        float4 a3 = *(const float4*)(kr + 36);
        bf16x8 f0, f1;
        f0[0] = f2b(a0.x); f0[1] = f2b(a0.y); f0[2] = f2b(a0.z); f0[3] = f2b(a0.w);
        f0[4] = f2b(a1.x); f0[5] = f2b(a1.y); f0[6] = f2b(a1.z); f0[7] = f2b(a1.w);
        f1[0] = f2b(a2.x); f1[1] = f2b(a2.y); f1[2] = f2b(a2.z); f1[3] = f2b(a2.w);
        f1[4] = f2b(a3.x); f1[5] = f2b(a3.y); f1[6] = f2b(a3.z); f1[7] = f2b(a3.w);
        kbf0[idx] = f0; kbf1[idx] = f1;
    } else if (blk < P_QW + P_WB + P_KB + P_W2) {
        int idx = (blk - P_QW - P_WB - P_KB) * 256 + tid;
        if (idx < 9 * 64 * 4) {
            int rp = idx & 3;
            int l  = (idx >> 2) & 63;
            int f  = idx >> 8;
            int m  = (f / 3) * 16 + (l & 15);
            int k0 = (f % 3) * 32 + 8 * (l >> 4) + 2 * rp;
            float a = (k0     < J1 && m < J2) ? W2[k0 * J2 + m]       : 0.0f;
            float b = (k0 + 1 < J1 && m < J2) ? W2[(k0 + 1) * J2 + m] : 0.0f;
            W2F[idx] = pack2(a, b);
        }
    } else {
        if (tid < 48) {
            b2p[tid] = (tid < J2) ? b2[tid] : 0.0f;
            W3p[tid] = (tid < J2) ? W3[tid] : 0.0f;
        }
    }
}

// ---- fused: block per bn, 4 waves; wave g owns tiles 4g..min(4g+4,13) ---
// Weights (20 WBF + 9 W2F frags = 116 VGPR) loaded ONCE per wave, resident
// across tiles (launch_bounds(256,2): 256-VGPR cap — R12's no-bounds build
// chose VGPR=56 and serialized 29 JIT weight loads per tile). Swapped-MFMA
// tile body verified in R12. In-block softmax+PV verified since R3.
__global__ __launch_bounds__(256, 2) void attn_f4(
        const float* __restrict__ queries, const float* __restrict__ keys,
        const int*   __restrict__ keys_length,
        const float* __restrict__ QW,
        const bf16x8* __restrict__ kbf0, const bf16x8* __restrict__ kbf1,
        const bf16x8* __restrict__ WBF, const bf16x8* __restrict__ W2F,
        const float* __restrict__ b2p, const float* __restrict__ W3p,
        const float* __restrict__ b3,
        float* __restrict__ out) {
    const int tid  = threadIdx.x;
    const int lane = tid & 63, wv = tid >> 6;            // 4 waves
    const int bn   = (blockIdx.x & 7) * 256 + (blockIdx.x >> 3);  // XCD swizzle
    const int b    = bn >> 4;
    const int cl   = lane & 15, rg = lane >> 4;

    __shared__ __align__(16) short X1[4][16][108];       // per-wave; 0 conflicts (R12)
    __shared__ float z3s[NTILE * 16];
    __shared__ float wsm[T_];
    __shared__ float part[256];
    __shared__ float red[8];

    // zero own-slice k-pad cols 80..95 (wave-local)
    #pragma unroll
    for (int i = 0; i < 4; ++i)
        X1[wv][rg + 4 * i][80 + cl] = 0;

    // ---- resident operands (loaded once) ----
    bf16x8 wbf[20];
    #pragma unroll
    for (int f = 0; f < 20; ++f) wbf[f] = WBF[f * 64 + lane];
    bf16x8 w2f[9];
    #pragma unroll
    for (int f = 0; f < 9; ++f) w2f[f] = W2F[f * 64 + lane];
    const float* qp = queries + bn * H_;
    float4 qa = *(const float4*)(qp + 8 * rg);
    float4 qb = *(const float4*)(qp + 8 * rg + 4);
    float4 qc = *(const float4*)(qp + 32 + 8 * rg);
    float4 qd = *(const float4*)(qp + 36 + 8 * rg);
    float4 b24[3], w34[3];
    #pragma unroll
    for (int nt = 0; nt < 3; ++nt) {
        b24[nt] = *(const float4*)(b2p + 16 * nt + 4 * rg);
        w34[nt] = *(const float4*)(W3p + 16 * nt + 4 * rg);
    }
    const float b3v = b3[0];

    // ---- tile loop: wave g does tiles 4g .. min(4g+4,13) ----
    const int mtEnd = (4 * wv + 4 < NTILE) ? 4 * wv + 4 : NTILE;
    #pragma unroll 1
    for (int mt = 4 * wv; mt < mtEnd; ++mt) {
        bf16x8 k0 = kbf0[(b * NTILE + mt) * 64 + lane];
        bf16x8 k1 = kbf1[(b * NTILE + mt) * 64 + lane];
        const uint4 kw0 = *(const uint4*)&k0;
        const uint4 kw1 = *(const uint4*)&k1;
        uint4 kqw0, kqw1;
        kqw0.x = kqword(kw0.x, qa.x, qa.y);
        kqw0.y = kqword(kw0.y, qa.z, qa.w);
        kqw0.z = kqword(kw0.z, qb.x, qb.y);
        kqw0.w = kqword(kw0.w, qb.z, qb.w);
        kqw1.x = kqword(kw1.x, qc.x, qc.y);
        kqw1.y = kqword(kw1.y, qc.z, qc.w);
        kqw1.z = kqword(kw1.z, qd.x, qd.y);
        kqw1.w = kqword(kw1.w, qd.z, qd.w);
        bf16x8 kq0 = *(bf16x8*)&kqw0;
        bf16x8 kq1 = *(bf16x8*)&kqw1;

        // layer 1 (swapped): acc[nt] = Z1^T rows j=16nt+4rg+i, col t=cl
        f32x4 acc[5];
        #pragma unroll
        for (int nt = 0; nt < 5; ++nt) {
            float4 qw4 = *(const float4*)(QW + bn * J1 + 16 * nt + 4 * rg);
            acc[nt][0] = qw4.x; acc[nt][1] = qw4.y; acc[nt][2] = qw4.z; acc[nt][3] = qw4.w;
        }
        #pragma unroll
        for (int nt = 0; nt < 5; ++nt) {
            acc[nt] = __builtin_amdgcn_mfma_f32_16x16x32_bf16(wbf[ 0 + nt], kq0, acc[nt], 0, 0, 0);
            acc[nt] = __builtin_amdgcn_mfma_f32_16x16x32_bf16(wbf[ 5 + nt], kq1, acc[nt], 0, 0, 0);
            acc[nt] = __builtin_amdgcn_mfma_f32_16x16x32_bf16(wbf[10 + nt], k0,  acc[nt], 0, 0, 0);
            acc[nt] = __builtin_amdgcn_mfma_f32_16x16x32_bf16(wbf[15 + nt], k1,  acc[nt], 0, 0, 0);
        }

        // sigmoid -> X1[t=cl][j]: 2 cvt_pk + 1 b64 write per nt
        #pragma unroll
        for (int nt = 0; nt < 5; ++nt) {
            unsigned r0 = cvtpk(sigmoidf_(acc[nt][0]), sigmoidf_(acc[nt][1]));
            unsigned r1 = cvtpk(sigmoidf_(acc[nt][2]), sigmoidf_(acc[nt][3]));
            *(uint2*)&X1[wv][cl][16 * nt + 4 * rg] = make_uint2(r0, r1);
        }

        // layer 2 (swapped): acc2[nt] = Z2^T rows m=16nt+4rg+i, col t=cl
        f32x4 acc2[3];
        #pragma unroll
        for (int nt = 0; nt < 3; ++nt) {
            acc2[nt][0] = b24[nt].x; acc2[nt][1] = b24[nt].y;
            acc2[nt][2] = b24[nt].z; acc2[nt][3] = b24[nt].w;
        }
        #pragma unroll
        for (int ks = 0; ks < 3; ++ks) {
            bf16x8 xa = *(const bf16x8*)&X1[wv][cl][8 * rg + 32 * ks];  // own row
            acc2[0] = __builtin_amdgcn_mfma_f32_16x16x32_bf16(w2f[0 + ks], xa, acc2[0], 0, 0, 0);
            acc2[1] = __builtin_amdgcn_mfma_f32_16x16x32_bf16(w2f[3 + ks], xa, acc2[1], 0, 0, 0);
            acc2[2] = __builtin_amdgcn_mfma_f32_16x16x32_bf16(w2f[6 + ks], xa, acc2[2], 0, 0, 0);
        }

        // layer 3: lane owns t=cl; 12 fma then 2 shfl over rg
        float p = 0.f;
        #pragma unroll
        for (int nt = 0; nt < 3; ++nt) {
            p = fmaf(sigmoidf_(acc2[nt][0]), w34[nt].x, p);
            p = fmaf(sigmoidf_(acc2[nt][1]), w34[nt].y, p);
            p = fmaf(sigmoidf_(acc2[nt][2]), w34[nt].z, p);
            p = fmaf(sigmoidf_(acc2[nt][3]), w34[nt].w, p);
        }
        p += __shfl_xor(p, 16);
        p += __shfl_xor(p, 32);
        if (rg == 0) z3s[mt * 16 + cl] = p + b3v;
    }
    __syncthreads();

    // ---- mask + scale + softmax (4-wave, verified) ----
    const int L = keys_length[b];
    float s = (tid < T_) ? ((tid < L) ? z3s[tid] : NEGV) * 0.125f : -3.0e38f;

    float mx = s;
    #pragma unroll
    for (int off = 32; off > 0; off >>= 1) mx = fmaxf(mx, __shfl_xor(mx, off));
    if ((tid & 63) == 0) red[tid >> 6] = mx;
    __syncthreads();
    mx = fmaxf(fmaxf(red[0], red[1]), fmaxf(red[2], red[3]));

    float e = (tid < T_) ? __expf(s - mx) : 0.0f;
    float sm = e;
    #pragma unroll
    for (int off = 32; off > 0; off >>= 1) sm += __shfl_xor(sm, off);
    __syncthreads();
    if ((tid & 63) == 0) red[4 + (tid >> 6)] = sm;
    __syncthreads();
    sm = red[4] + red[5] + red[6] + red[7];

    if (tid < T_) wsm[tid] = e / sm;
    __syncthreads();

    // ---- out[h] = sum_t w[t] * keys[b][t][h] (L2-hot, coalesced) ----
    const float* kb = keys + (size_t)b * T_ * H_;
    {
        int h = tid & 63, pw = tid >> 6;
        float acc = 0.f;
        int tb = pw * 50;
        #pragma unroll 5
        for (int t = tb; t < tb + 50; ++t)
            acc = fmaf(wsm[t], kb[(size_t)t * H_ + h], acc);
        part[tid] = acc;
    }
    __syncthreads();
    if (tid < 64) {
        out[bn * H_ + tid] = part[tid] + part[64 + tid] + part[128 + tid] + part[192 + tid];
    }
}

// --- fallback (no workspace): round-3 verified pure-VALU kernel ----------
__global__ __launch_bounds__(256, 3) void attn_nows(
        const float* __restrict__ queries, const float* __restrict__ keys,
        const int*   __restrict__ keys_length,
        const float* __restrict__ W1, const float* __restrict__ b1,
        const float* __restrict__ W2, const float* __restrict__ b2,
        const float* __restrict__ W3, const float* __restrict__ b3,
        float* __restrict__ out) {
    const int tid = threadIdx.x;
    const int bn = (blockIdx.x & 7) * 256 + (blockIdx.x >> 3);
    const int b  = bn >> 4;

    __shared__ float kT[H_][T_ + 1];
    __shared__ float wsm[T_];
    __shared__ float part[256];
    __shared__ float red[8];
    __shared__ float QWq[J1];

    for (int idx = tid; idx < T_ * H_; idx += 256) {
        int t = idx >> 6, h = idx & 63;
        kT[h][t] = keys[(b * T_ + t) * H_ + h];
    }
    if (tid < J1) {
        float acc = b1[tid];
        const float* qp = queries + bn * H_;
        for (int h = 0; h < H_; ++h)
            acc = fmaf(qp[h], W1[h * J1 + tid] + W1[(128 + h) * J1 + tid], acc);
        QWq[tid] = acc;
    }
    __syncthreads();

    const int tt = (tid < T_) ? tid : 0;
    const float* qp = queries + bn * H_;

    float qk[H_];
    #pragma unroll
    for (int h = 0; h < H_; ++h) qk[h] = qp[h] * kT[h][tt];

    float z2[J2];
    #pragma unroll
    for (int m = 0; m < J2; ++m) z2[m] = b2[m];

    #pragma unroll 1
    for (int c = 0; c < 4; ++c) {
        const int j0 = c * 20;
        float z1c[20];
        #pragma unroll
        for (int j = 0; j < 20; ++j) z1c[j] = QWq[j0 + j];
        #pragma unroll
        for (int h = 0; h < H_; ++h) {
            float kh = kT[h][tt];
            const float* Wd = W1 + (192 + h) * J1 + j0;
            const float* Wb = W1 + (64 + h) * J1 + j0;
            const float* Wc = W1 + (128 + h) * J1 + j0;
            #pragma unroll
            for (int j = 0; j < 20; ++j)
                z1c[j] = fmaf(qk[h], Wd[j], fmaf(kh, Wb[j] - Wc[j], z1c[j]));
        }
        #pragma unroll
        for (int j = 0; j < 20; ++j) {
            float x = sigmoidf_(z1c[j]);
            const float* w2 = W2 + (j0 + j) * J2;
            #pragma unroll
            for (int m = 0; m < J2; ++m) z2[m] = fmaf(x, w2[m], z2[m]);
        }
    }

    float z3 = b3[0];
    #pragma unroll
    for (int m = 0; m < J2; ++m) z3 = fmaf(sigmoidf_(z2[m]), W3[m], z3);

    const int L = keys_length[b];
    float s = (tid < T_) ? ((tid < L) ? z3 : NEGV) * 0.125f : -3.0e38f;

    float mx = s;
    #pragma unroll
    for (int off = 32; off > 0; off >>= 1) mx = fmaxf(mx, __shfl_xor(mx, off));
    if ((tid & 63) == 0) red[tid >> 6] = mx;
    __syncthreads();
    mx = fmaxf(fmaxf(red[0], red[1]), fmaxf(red[2], red[3]));

    float e = (tid < T_) ? __expf(s - mx) : 0.0f;
    float sm = e;
    #pragma unroll
    for (int off = 32; off > 0; off >>= 1) sm += __shfl_xor(sm, off);
    __syncthreads();
    if ((tid & 63) == 0) red[4 + (tid >> 6)] = sm;
    __syncthreads();
    sm = red[4] + red[5] + red[6] + red[7];

    if (tid < T_) wsm[tid] = e / sm;
    __syncthreads();

    {
        int h = tid & 63, p = tid >> 6;
        float acc = 0.f;
        int t0 = p * 50;
        for (int t = t0; t < t0 + 50; ++t)
            acc = fmaf(wsm[t], kT[h][t], acc);
        part[tid] = acc;
    }
    __syncthreads();
    if (tid < 64) {
        out[bn * H_ + tid] = part[tid] + part[64 + tid] + part[128 + tid] + part[192 + tid];
    }
}

extern "C" void kernel_launch(void* const* d_in, const int* in_sizes, int n_in,
                              void* d_out, int out_size, void* d_ws, size_t ws_size,
                              hipStream_t stream) {
    const float* queries = (const float*)d_in[0];
    const float* keys    = (const float*)d_in[1];
    const int*   klen    = (const int*)  d_in[2];
    const float* W1 = (const float*)d_in[3];
    const float* b1 = (const float*)d_in[4];
    const float* W2 = (const float*)d_in[5];
    const float* b2 = (const float*)d_in[6];
    const float* W3 = (const float*)d_in[7];
    const float* b3 = (const float*)d_in[8];
    float* out = (float*)d_out;

    // ws layout (16B multiples):
    // QW   [2048*80 f32]   =   655,360 B
    // kbf0 [106496 x 16B]  = 1,703,936 B
    // kbf1 [106496 x 16B]  = 1,703,936 B
    // WBF  [20*64 x 16B]   =    20,480 B
    // W2F  [2304 u32]      =     9,216 B
    // b2p/W3p [64 f32 each]=       512 B
    const size_t nkbf = (size_t)B_ * NTILE * 64;
    const size_t need = 655360 + 2 * 1703936 + 20480 + 9216 + 512;

    if (ws_size >= need) {
        char* base = (char*)d_ws;
        float*  QW   = (float*)base;
        bf16x8* kbf0 = (bf16x8*)(base + 655360);
        bf16x8* kbf1 = kbf0 + nkbf;
        bf16x8* WBF  = kbf1 + nkbf;
        unsigned* W2F = (unsigned*)((char*)WBF + 20480);
        float*  b2p  = (float*)((char*)W2F + 9216);
        float*  W3p  = b2p + 64;

        prep<<<dim3(P_QW + P_WB + P_KB + P_W2 + P_PB), dim3(256), 0, stream>>>(
            queries, keys, W1, b1, W2, b2, W3,
            QW, (unsigned*)WBF, kbf0, kbf1, W2F, b2p, W3p);
        attn_f4<<<dim3(B_ * N_), dim3(256), 0, stream>>>(
            queries, keys, klen, QW, kbf0, kbf1, WBF, (const bf16x8*)W2F,
            b2p, W3p, b3, out);
    } else {
        attn_nows<<<dim3(B_ * N_), dim3(256), 0, stream>>>(
            queries, keys, klen, W1, b1, W2, b2, W3, b3, out);
    }
}

// Round 14
// 55.585 us; speedup vs baseline: 1.1573x; 1.1573x over previous
//
#include <hip/hip_runtime.h>
#include <hip/hip_bf16.h>
#include <math.h>

#define B_  128
#define N_  16
#define T_  200
#define H_  64
#define J1  80
#define J2  40
#define NTILE 13
#define NEGV -4294967295.0f   // -2^32 + 1

typedef __attribute__((ext_vector_type(8))) short bf16x8;
typedef __attribute__((ext_vector_type(4))) float f32x4;

__device__ __forceinline__ float sigmoidf_(float x) {
    return 1.0f / (1.0f + __expf(-x));
}
// branch-free RNE f32->bf16 (finite inputs only)
__device__ __forceinline__ short f2b(float x) {
    unsigned u = __float_as_uint(x);
    return (short)((u + 0x7FFF + ((u >> 16) & 1)) >> 16);
}
__device__ __forceinline__ unsigned pack2(float a, float b) {
    return (unsigned)(unsigned short)f2b(a) | ((unsigned)(unsigned short)f2b(b) << 16);
}
// HW packed convert: dst = {lo16: bf16(a), hi16: bf16(b)}
__device__ __forceinline__ unsigned cvtpk(float a, float b) {
    unsigned r;
    asm("v_cvt_pk_bf16_f32 %0, %1, %2" : "=v"(r) : "v"(a), "v"(b));
    return r;
}
// kq word: in-register bf16 extract + mul + cvt_pk = 5 VALU
__device__ __forceinline__ unsigned kqword(unsigned w, float ql, float qh) {
    float lo = __uint_as_float(w << 16) * ql;
    float hi = __uint_as_float(w & 0xffff0000u) * qh;
    return cvtpk(lo, hi);
}

// ---- prep: ONE dispatch, 5 ranges (verified R12/R13) ---------------------
#define P_QW 160
#define P_WB 20
#define P_KB 416
#define P_W2 9
#define P_PB 1
__global__ void prep(const float* __restrict__ queries,
                     const float* __restrict__ keys,
                     const float* __restrict__ W1,
                     const float* __restrict__ b1,
                     const float* __restrict__ W2,
                     const float* __restrict__ b2,
                     const float* __restrict__ W3,
                     float* __restrict__ QW,
                     unsigned* __restrict__ WBFu,
                     bf16x8* __restrict__ kbf0, bf16x8* __restrict__ kbf1,
                     unsigned* __restrict__ W2F,
                     float* __restrict__ b2p, float* __restrict__ W3p) {
    const int blk = blockIdx.x, tid = threadIdx.x;
    if (blk < P_QW) {
        int idx = blk * 256 + tid;                 // (bn, j/4), exact
        int bn = idx / 20, j = (idx % 20) * 4;
        float4 acc = *(const float4*)(b1 + j);
        const float* qp = queries + bn * H_;
        for (int h = 0; h < H_; ++h) {
            float qh = qp[h];
            float4 wa = *(const float4*)(W1 + h * J1 + j);
            float4 wc = *(const float4*)(W1 + (128 + h) * J1 + j);
            acc.x = fmaf(qh, wa.x + wc.x, acc.x);
            acc.y = fmaf(qh, wa.y + wc.y, acc.y);
            acc.z = fmaf(qh, wa.z + wc.z, acc.z);
            acc.w = fmaf(qh, wa.w + wc.w, acc.w);
        }
        *(float4*)(QW + bn * J1 + j) = acc;
    } else if (blk < P_QW + P_WB) {
        int idx = (blk - P_QW) * 256 + tid;        // = fi*256 + l*4 + rp, exact
        int rp = idx & 3, l = (idx >> 2) & 63, fi = idx >> 8;
        int j  = (fi % 5) * 16 + (l & 15);
        int R  = (fi / 5) * 32 + 8 * (l >> 4) + 2 * rp;
        float a, b;
        if (R < 64) {
            a = W1[(192 + R) * J1 + j];
            b = W1[(193 + R) * J1 + j];
        } else {
            int r2 = R - 64;
            a = W1[(64 + r2) * J1 + j] - W1[(128 + r2) * J1 + j];
            b = W1[(65 + r2) * J1 + j] - W1[(129 + r2) * J1 + j];
        }
        WBFu[idx] = pack2(a, b);
    } else if (blk < P_QW + P_WB + P_KB) {
        int idx = (blk - P_QW - P_WB) * 256 + tid; // (b*13+mt)*64+l, exact
        int l  = idx & 63, bm = idx >> 6;
        int mt = bm % NTILE, b = bm / NTILE;
        int t  = mt * 16 + (l & 15); if (t > T_ - 1) t = T_ - 1;
        int rg = l >> 4;
        const float* kr = keys + ((size_t)(b * T_ + t)) * H_ + 8 * rg;
        float4 a0 = *(const float4*)(kr);
        float4 a1 = *(const float4*)(kr + 4);
        float4 a2 = *(const float4*)(kr + 32);
        float4 a3 = *(const float4*)(kr + 36);
        bf16x8 f0, f1;
        f0[0] = f2b(a0.x); f0[1] = f2b(a0.y); f0[2] = f2b(a0.z); f0[3] = f2b(a0.w);
        f0[4] = f2b(a1.x); f0[5] = f2b(a1.y); f0[6] = f2b(a1.z); f0[7] = f2b(a1.w);
        f1[0] = f2b(a2.x); f1[1] = f2b(a2.y); f1[2] = f2b(a2.z); f1[3] = f2b(a2.w);
        f1[4] = f2b(a3.x); f1[5] = f2b(a3.y); f1[6] = f2b(a3.z); f1[7] = f2b(a3.w);
        kbf0[idx] = f0; kbf1[idx] = f1;
    } else if (blk < P_QW + P_WB + P_KB + P_W2) {
        int idx = (blk - P_QW - P_WB - P_KB) * 256 + tid;
        if (idx < 9 * 64 * 4) {
            int rp = idx & 3;
            int l  = (idx >> 2) & 63;
            int f  = idx >> 8;
            int m  = (f / 3) * 16 + (l & 15);
            int k0 = (f % 3) * 32 + 8 * (l >> 4) + 2 * rp;
            float a = (k0     < J1 && m < J2) ? W2[k0 * J2 + m]       : 0.0f;
            float b = (k0 + 1 < J1 && m < J2) ? W2[(k0 + 1) * J2 + m] : 0.0f;
            W2F[idx] = pack2(a, b);
        }
    } else {
        if (tid < 48) {
            b2p[tid] = (tid < J2) ? b2[tid] : 0.0f;
            W3p[tid] = (tid < J2) ? W3[tid] : 0.0f;
        }
    }
}

// ---- fused: WAVE per bn; weights in LDS (staged once); no barriers after.
// Wave loops its 13 tiles (swapped-MFMA body verified R12), z -> LDS, then
// in-wave softmax (lane owns 4 of 208 slots) + in-wave PV. 2048 waves =
// exactly 2/SIMD resident — single round, zero tail, zero inter-wave sync.
__global__ __launch_bounds__(256, 2) void attn_wv(
        const float* __restrict__ queries, const float* __restrict__ keys,
        const int*   __restrict__ keys_length,
        const float* __restrict__ QW,
        const bf16x8* __restrict__ kbf0, const bf16x8* __restrict__ kbf1,
        const bf16x8* __restrict__ WALL,   // WBF(20 frags) ++ W2F(9 frags)
        const float* __restrict__ b2p, const float* __restrict__ W3p,
        const float* __restrict__ b3,
        float* __restrict__ out) {
    const int tid  = threadIdx.x;
    const int lane = tid & 63, wv = tid >> 6;            // 4 waves
    const int blk  = (blockIdx.x & 7) * 64 + (blockIdx.x >> 3);  // 512 = 8*64
    const int bn   = blk * 4 + wv;                       // wave owns one bn
    const int b    = bn >> 4;
    const int cl   = lane & 15, rg = lane >> 4;

    __shared__ __align__(16) short wlds[29 * 64 * 8];    // 29,696 B weights
    __shared__ __align__(16) short X1[4][16][108];       // 13,824 B (R12: 0 conflicts)
    __shared__ float wsm[4][208];                        //  3,328 B

    // ---- stage ALL weights to LDS once; the only barrier in the kernel ----
    for (int i = tid; i < 29 * 64; i += 256)
        ((bf16x8*)wlds)[i] = WALL[i];
    // zero own-wave X1 k-pad cols 80..95
    #pragma unroll
    for (int i = 0; i < 4; ++i)
        X1[wv][rg + 4 * i][80 + cl] = 0;
    __syncthreads();

    const bf16x8* wl = (const bf16x8*)wlds;              // [0,20)=WBF, [20,29)=W2F

    // ---- hoisted per-wave constants ----
    const float* qp = queries + bn * H_;
    float4 qa = *(const float4*)(qp + 8 * rg);
    float4 qb = *(const float4*)(qp + 8 * rg + 4);
    float4 qc = *(const float4*)(qp + 32 + 8 * rg);
    float4 qd = *(const float4*)(qp + 36 + 8 * rg);
    float4 qw4[5];
    #pragma unroll
    for (int nt = 0; nt < 5; ++nt)
        qw4[nt] = *(const float4*)(QW + bn * J1 + 16 * nt + 4 * rg);
    float4 b24[3], w34[3];
    #pragma unroll
    for (int nt = 0; nt < 3; ++nt) {
        b24[nt] = *(const float4*)(b2p + 16 * nt + 4 * rg);
        w34[nt] = *(const float4*)(W3p + 16 * nt + 4 * rg);
    }
    const float b3v = b3[0];
    const float* kb = keys + (size_t)b * T_ * H_;

    // ---- tile loop (rolled; mt feeds only addresses + LDS index) ----
    bf16x8 nk0 = kbf0[(b * NTILE) * 64 + lane];          // prefetch tile 0
    bf16x8 nk1 = kbf1[(b * NTILE) * 64 + lane];
    #pragma unroll 1
    for (int mt = 0; mt < NTILE; ++mt) {
        bf16x8 k0 = nk0, k1 = nk1;
        {   // prefetch next tile (clamped; named regs, rule #20 safe)
            int mn = mt + 1 < NTILE ? mt + 1 : NTILE - 1;
            nk0 = kbf0[(b * NTILE + mn) * 64 + lane];
            nk1 = kbf1[(b * NTILE + mn) * 64 + lane];
        }
        const uint4 kw0 = *(const uint4*)&k0;
        const uint4 kw1 = *(const uint4*)&k1;
        uint4 kqw0, kqw1;
        kqw0.x = kqword(kw0.x, qa.x, qa.y);
        kqw0.y = kqword(kw0.y, qa.z, qa.w);
        kqw0.z = kqword(kw0.z, qb.x, qb.y);
        kqw0.w = kqword(kw0.w, qb.z, qb.w);
        kqw1.x = kqword(kw1.x, qc.x, qc.y);
        kqw1.y = kqword(kw1.y, qc.z, qc.w);
        kqw1.z = kqword(kw1.z, qd.x, qd.y);
        kqw1.w = kqword(kw1.w, qd.z, qd.w);
        bf16x8 kq0 = *(bf16x8*)&kqw0;
        bf16x8 kq1 = *(bf16x8*)&kqw1;

        // layer 1 (swapped): acc[nt] = Z1^T rows j=16nt+4rg+i, col t=cl
        f32x4 acc[5];
        #pragma unroll
        for (int nt = 0; nt < 5; ++nt) {
            acc[nt][0] = qw4[nt].x; acc[nt][1] = qw4[nt].y;
            acc[nt][2] = qw4[nt].z; acc[nt][3] = qw4[nt].w;
        }
        #pragma unroll
        for (int nt = 0; nt < 5; ++nt) {
            acc[nt] = __builtin_amdgcn_mfma_f32_16x16x32_bf16(wl[( 0 + nt) * 64 + lane], kq0, acc[nt], 0, 0, 0);
            acc[nt] = __builtin_amdgcn_mfma_f32_16x16x32_bf16(wl[( 5 + nt) * 64 + lane], kq1, acc[nt], 0, 0, 0);
            acc[nt] = __builtin_amdgcn_mfma_f32_16x16x32_bf16(wl[(10 + nt) * 64 + lane], k0,  acc[nt], 0, 0, 0);
            acc[nt] = __builtin_amdgcn_mfma_f32_16x16x32_bf16(wl[(15 + nt) * 64 + lane], k1,  acc[nt], 0, 0, 0);
        }

        // sigmoid -> X1[t=cl][j]: 2 cvt_pk + 1 b64 write per nt
        #pragma unroll
        for (int nt = 0; nt < 5; ++nt) {
            unsigned r0 = cvtpk(sigmoidf_(acc[nt][0]), sigmoidf_(acc[nt][1]));
            unsigned r1 = cvtpk(sigmoidf_(acc[nt][2]), sigmoidf_(acc[nt][3]));
            *(uint2*)&X1[wv][cl][16 * nt + 4 * rg] = make_uint2(r0, r1);
        }

        // layer 2 (swapped): acc2[nt] = Z2^T rows m=16nt+4rg+i, col t=cl
        f32x4 acc2[3];
        #pragma unroll
        for (int nt = 0; nt < 3; ++nt) {
            acc2[nt][0] = b24[nt].x; acc2[nt][1] = b24[nt].y;
            acc2[nt][2] = b24[nt].z; acc2[nt][3] = b24[nt].w;
        }
        #pragma unroll
        for (int ks = 0; ks < 3; ++ks) {
            bf16x8 xa = *(const bf16x8*)&X1[wv][cl][8 * rg + 32 * ks];
            acc2[0] = __builtin_amdgcn_mfma_f32_16x16x32_bf16(wl[(20 + 0 + ks) * 64 + lane], xa, acc2[0], 0, 0, 0);
            acc2[1] = __builtin_amdgcn_mfma_f32_16x16x32_bf16(wl[(20 + 3 + ks) * 64 + lane], xa, acc2[1], 0, 0, 0);
            acc2[2] = __builtin_amdgcn_mfma_f32_16x16x32_bf16(wl[(20 + 6 + ks) * 64 + lane], xa, acc2[2], 0, 0, 0);
        }

        // layer 3: lane owns t=cl; 12 fma then 2 shfl over rg
        float p = 0.f;
        #pragma unroll
        for (int nt = 0; nt < 3; ++nt) {
            p = fmaf(sigmoidf_(acc2[nt][0]), w34[nt].x, p);
            p = fmaf(sigmoidf_(acc2[nt][1]), w34[nt].y, p);
            p = fmaf(sigmoidf_(acc2[nt][2]), w34[nt].z, p);
            p = fmaf(sigmoidf_(acc2[nt][3]), w34[nt].w, p);
        }
        p += __shfl_xor(p, 16);
        p += __shfl_xor(p, 32);
        if (rg == 0) wsm[wv][mt * 16 + cl] = p + b3v;    // raw z3 (runtime LDS ok)
    }

    // ---- in-wave softmax: lane owns slots t = lane, +64, +128, +192 ----
    const int L  = keys_length[b];
    const int t0 = lane, t1 = lane + 64, t2 = lane + 128, t3 = lane + 192;
    float r0 = wsm[wv][t0], r1 = wsm[wv][t1], r2 = wsm[wv][t2];
    float r3 = (t3 < 208) ? wsm[wv][t3] : 0.0f;
    float s0 = (t0 < L) ? r0 * 0.125f : NEGV * 0.125f;
    float s1 = (t1 < L) ? r1 * 0.125f : NEGV * 0.125f;
    float s2 = (t2 < L) ? r2 * 0.125f : NEGV * 0.125f;
    float s3 = (t3 < T_ && t3 < L) ? r3 * 0.125f : ((t3 < T_) ? NEGV * 0.125f : -3.0e38f);

    float mx = fmaxf(fmaxf(s0, s1), fmaxf(s2, s3));
    #pragma unroll
    for (int off = 32; off > 0; off >>= 1) mx = fmaxf(mx, __shfl_xor(mx, off));

    float e0 = __expf(s0 - mx);
    float e1 = __expf(s1 - mx);
    float e2 = __expf(s2 - mx);
    float e3 = (t3 < T_) ? __expf(s3 - mx) : 0.0f;
    float sm = e0 + e1 + e2 + e3;
    #pragma unroll
    for (int off = 32; off > 0; off >>= 1) sm += __shfl_xor(sm, off);

    float inv = 1.0f / sm;
    wsm[wv][t0] = e0 * inv;
    wsm[wv][t1] = e1 * inv;
    wsm[wv][t2] = e2 * inv;
    if (t3 < T_) wsm[wv][t3] = e3 * inv;                  // t>=200 never read

    // ---- in-wave PV: out[h=lane] = sum_t w[t] * keys[b][t][h] ----
    float acc_ = 0.f;
    #pragma unroll 8
    for (int t = 0; t < T_; ++t)
        acc_ = fmaf(wsm[wv][t], kb[(size_t)t * H_ + lane], acc_);
    out[bn * H_ + lane] = acc_;
}

// --- fallback (no workspace): round-3 verified pure-VALU kernel ----------
__global__ __launch_bounds__(256, 3) void attn_nows(
        const float* __restrict__ queries, const float* __restrict__ keys,
        const int*   __restrict__ keys_length,
        const float* __restrict__ W1, const float* __restrict__ b1,
        const float* __restrict__ W2, const float* __restrict__ b2,
        const float* __restrict__ W3, const float* __restrict__ b3,
        float* __restrict__ out) {
    const int tid = threadIdx.x;
    const int bn = (blockIdx.x & 7) * 256 + (blockIdx.x >> 3);
    const int b  = bn >> 4;

    __shared__ float kT[H_][T_ + 1];
    __shared__ float wsm[T_];
    __shared__ float part[256];
    __shared__ float red[8];
    __shared__ float QWq[J1];

    for (int idx = tid; idx < T_ * H_; idx += 256) {
        int t = idx >> 6, h = idx & 63;
        kT[h][t] = keys[(b * T_ + t) * H_ + h];
    }
    if (tid < J1) {
        float acc = b1[tid];
        const float* qp = queries + bn * H_;
        for (int h = 0; h < H_; ++h)
            acc = fmaf(qp[h], W1[h * J1 + tid] + W1[(128 + h) * J1 + tid], acc);
        QWq[tid] = acc;
    }
    __syncthreads();

    const int tt = (tid < T_) ? tid : 0;
    const float* qp = queries + bn * H_;

    float qk[H_];
    #pragma unroll
    for (int h = 0; h < H_; ++h) qk[h] = qp[h] * kT[h][tt];

    float z2[J2];
    #pragma unroll
    for (int m = 0; m < J2; ++m) z2[m] = b2[m];

    #pragma unroll 1
    for (int c = 0; c < 4; ++c) {
        const int j0 = c * 20;
        float z1c[20];
        #pragma unroll
        for (int j = 0; j < 20; ++j) z1c[j] = QWq[j0 + j];
        #pragma unroll
        for (int h = 0; h < H_; ++h) {
            float kh = kT[h][tt];
            const float* Wd = W1 + (192 + h) * J1 + j0;
            const float* Wb = W1 + (64 + h) * J1 + j0;
            const float* Wc = W1 + (128 + h) * J1 + j0;
            #pragma unroll
            for (int j = 0; j < 20; ++j)
                z1c[j] = fmaf(qk[h], Wd[j], fmaf(kh, Wb[j] - Wc[j], z1c[j]));
        }
        #pragma unroll
        for (int j = 0; j < 20; ++j) {
            float x = sigmoidf_(z1c[j]);
            const float* w2 = W2 + (j0 + j) * J2;
            #pragma unroll
            for (int m = 0; m < J2; ++m) z2[m] = fmaf(x, w2[m], z2[m]);
        }
    }

    float z3 = b3[0];
    #pragma unroll
    for (int m = 0; m < J2; ++m) z3 = fmaf(sigmoidf_(z2[m]), W3[m], z3);

    const int L = keys_length[b];
    float s = (tid < T_) ? ((tid < L) ? z3 : NEGV) * 0.125f : -3.0e38f;

    float mx = s;
    #pragma unroll
    for (int off = 32; off > 0; off >>= 1) mx = fmaxf(mx, __shfl_xor(mx, off));
    if ((tid & 63) == 0) red[tid >> 6] = mx;
    __syncthreads();
    mx = fmaxf(fmaxf(red[0], red[1]), fmaxf(red[2], red[3]));

    float e = (tid < T_) ? __expf(s - mx) : 0.0f;
    float sm = e;
    #pragma unroll
    for (int off = 32; off > 0; off >>= 1) sm += __shfl_xor(sm, off);
    __syncthreads();
    if ((tid & 63) == 0) red[4 + (tid >> 6)] = sm;
    __syncthreads();
    sm = red[4] + red[5] + red[6] + red[7];

    if (tid < T_) wsm[tid] = e / sm;
    __syncthreads();

    {
        int h = tid & 63, p = tid >> 6;
        float acc = 0.f;
        int t0 = p * 50;
        for (int t = t0; t < t0 + 50; ++t)
            acc = fmaf(wsm[t], kT[h][t], acc);
        part[tid] = acc;
    }
    __syncthreads();
    if (tid < 64) {
        out[bn * H_ + tid] = part[tid] + part[64 + tid] + part[128 + tid] + part[192 + tid];
    }
}

extern "C" void kernel_launch(void* const* d_in, const int* in_sizes, int n_in,
                              void* d_out, int out_size, void* d_ws, size_t ws_size,
                              hipStream_t stream) {
    const float* queries = (const float*)d_in[0];
    const float* keys    = (const float*)d_in[1];
    const int*   klen    = (const int*)  d_in[2];
    const float* W1 = (const float*)d_in[3];
    const float* b1 = (const float*)d_in[4];
    const float* W2 = (const float*)d_in[5];
    const float* b2 = (const float*)d_in[6];
    const float* W3 = (const float*)d_in[7];
    const float* b3 = (const float*)d_in[8];
    float* out = (float*)d_out;

    // ws layout (16B multiples; WBF and W2F CONTIGUOUS for single coop copy):
    // QW   [2048*80 f32]   =   655,360 B
    // kbf0 [106496 x 16B]  = 1,703,936 B
    // kbf1 [106496 x 16B]  = 1,703,936 B
    // WBF  [20*64 x 16B]   =    20,480 B   <- WALL starts here
    // W2F  [2304 u32]      =     9,216 B   <- contiguous after WBF
    // b2p/W3p [64 f32 each]=       512 B
    const size_t nkbf = (size_t)B_ * NTILE * 64;
    const size_t need = 655360 + 2 * 1703936 + 20480 + 9216 + 512;

    if (ws_size >= need) {
        char* base = (char*)d_ws;
        float*  QW   = (float*)base;
        bf16x8* kbf0 = (bf16x8*)(base + 655360);
        bf16x8* kbf1 = kbf0 + nkbf;
        bf16x8* WBF  = kbf1 + nkbf;
        unsigned* W2F = (unsigned*)((char*)WBF + 20480);
        float*  b2p  = (float*)((char*)W2F + 9216);
        float*  W3p  = b2p + 64;

        prep<<<dim3(P_QW + P_WB + P_KB + P_W2 + P_PB), dim3(256), 0, stream>>>(
            queries, keys, W1, b1, W2, b2, W3,
            QW, (unsigned*)WBF, kbf0, kbf1, W2F, b2p, W3p);
        attn_wv<<<dim3(512), dim3(256), 0, stream>>>(
            queries, keys, klen, QW, kbf0, kbf1, WBF, b2p, W3p, b3, out);
    } else {
        attn_nows<<<dim3(B_ * N_), dim3(256), 0, stream>>>(
            queries, keys, klen, W1, b1, W2, b2, W3, b3, out);
    }
}

// Round 15
// 39.724 us; speedup vs baseline: 1.6194x; 1.3993x over previous
//
#include <hip/hip_runtime.h>
#include <hip/hip_bf16.h>
#include <math.h>

#define B_  128
#define N_  16
#define T_  200
#define H_  64
#define J1  80
#define J2  40
#define NTILE 13
#define NEGV -4294967295.0f   // -2^32 + 1

typedef __attribute__((ext_vector_type(8))) short bf16x8;
typedef __attribute__((ext_vector_type(4))) float f32x4;

// fast sigmoid: v_rcp_f32 (1 ulp) instead of the ~10-op f32 div expansion
__device__ __forceinline__ float sigmoidf_(float x) {
    return __builtin_amdgcn_rcpf(1.0f + __expf(-x));
}
// branch-free RNE f32->bf16 (finite inputs only)
__device__ __forceinline__ short f2b(float x) {
    unsigned u = __float_as_uint(x);
    return (short)((u + 0x7FFF + ((u >> 16) & 1)) >> 16);
}
__device__ __forceinline__ unsigned pack2(float a, float b) {
    return (unsigned)(unsigned short)f2b(a) | ((unsigned)(unsigned short)f2b(b) << 16);
}
// HW packed convert: dst = {lo16: bf16(a), hi16: bf16(b)}
__device__ __forceinline__ unsigned cvtpk(float a, float b) {
    unsigned r;
    asm("v_cvt_pk_bf16_f32 %0, %1, %2" : "=v"(r) : "v"(a), "v"(b));
    return r;
}
// kq word: in-register bf16 extract + mul + cvt_pk = 5 VALU
__device__ __forceinline__ unsigned kqword(unsigned w, float ql, float qh) {
    float lo = __uint_as_float(w << 16) * ql;
    float hi = __uint_as_float(w & 0xffff0000u) * qh;
    return cvtpk(lo, hi);
}

// ---- prep: ONE dispatch, 5 ranges (verified R12-R14) ---------------------
#define P_QW 160
#define P_WB 20
#define P_KB 416
#define P_W2 9
#define P_PB 1
__global__ void prep(const float* __restrict__ queries,
                     const float* __restrict__ keys,
                     const float* __restrict__ W1,
                     const float* __restrict__ b1,
                     const float* __restrict__ W2,
                     const float* __restrict__ b2,
                     const float* __restrict__ W3,
                     float* __restrict__ QW,
                     unsigned* __restrict__ WBFu,
                     bf16x8* __restrict__ kbf0, bf16x8* __restrict__ kbf1,
                     unsigned* __restrict__ W2F,
                     float* __restrict__ b2p, float* __restrict__ W3p) {
    const int blk = blockIdx.x, tid = threadIdx.x;
    if (blk < P_QW) {
        int idx = blk * 256 + tid;                 // (bn, j/4), exact
        int bn = idx / 20, j = (idx % 20) * 4;
        float4 acc = *(const float4*)(b1 + j);
        const float* qp = queries + bn * H_;
        for (int h = 0; h < H_; ++h) {
            float qh = qp[h];
            float4 wa = *(const float4*)(W1 + h * J1 + j);
            float4 wc = *(const float4*)(W1 + (128 + h) * J1 + j);
            acc.x = fmaf(qh, wa.x + wc.x, acc.x);
            acc.y = fmaf(qh, wa.y + wc.y, acc.y);
            acc.z = fmaf(qh, wa.z + wc.z, acc.z);
            acc.w = fmaf(qh, wa.w + wc.w, acc.w);
        }
        *(float4*)(QW + bn * J1 + j) = acc;
    } else if (blk < P_QW + P_WB) {
        int idx = (blk - P_QW) * 256 + tid;        // = fi*256 + l*4 + rp, exact
        int rp = idx & 3, l = (idx >> 2) & 63, fi = idx >> 8;
        int j  = (fi % 5) * 16 + (l & 15);
        int R  = (fi / 5) * 32 + 8 * (l >> 4) + 2 * rp;
        float a, b;
        if (R < 64) {
            a = W1[(192 + R) * J1 + j];
            b = W1[(193 + R) * J1 + j];
        } else {
            int r2 = R - 64;
            a = W1[(64 + r2) * J1 + j] - W1[(128 + r2) * J1 + j];
            b = W1[(65 + r2) * J1 + j] - W1[(129 + r2) * J1 + j];
        }
        WBFu[idx] = pack2(a, b);
    } else if (blk < P_QW + P_WB + P_KB) {
        int idx = (blk - P_QW - P_WB) * 256 + tid; // (b*13+mt)*64+l, exact
        int l  = idx & 63, bm = idx >> 6;
        int mt = bm % NTILE, b = bm / NTILE;
        int t  = mt * 16 + (l & 15); if (t > T_ - 1) t = T_ - 1;
        int rg = l >> 4;
        const float* kr = keys + ((size_t)(b * T_ + t)) * H_ + 8 * rg;
        float4 a0 = *(const float4*)(kr);
        float4 a1 = *(const float4*)(kr + 4);
        float4 a2 = *(const float4*)(kr + 32);
        float4 a3 = *(const float4*)(kr + 36);
        bf16x8 f0, f1;
        f0[0] = f2b(a0.x); f0[1] = f2b(a0.y); f0[2] = f2b(a0.z); f0[3] = f2b(a0.w);
        f0[4] = f2b(a1.x); f0[5] = f2b(a1.y); f0[6] = f2b(a1.z); f0[7] = f2b(a1.w);
        f1[0] = f2b(a2.x); f1[1] = f2b(a2.y); f1[2] = f2b(a2.z); f1[3] = f2b(a2.w);
        f1[4] = f2b(a3.x); f1[5] = f2b(a3.y); f1[6] = f2b(a3.z); f1[7] = f2b(a3.w);
        kbf0[idx] = f0; kbf1[idx] = f1;
    } else if (blk < P_QW + P_WB + P_KB + P_W2) {
        int idx = (blk - P_QW - P_WB - P_KB) * 256 + tid;
        if (idx < 9 * 64 * 4) {
            int rp = idx & 3;
            int l  = (idx >> 2) & 63;
            int f  = idx >> 8;
            int m  = (f / 3) * 16 + (l & 15);
            int k0 = (f % 3) * 32 + 8 * (l >> 4) + 2 * rp;
            float a = (k0     < J1 && m < J2) ? W2[k0 * J2 + m]       : 0.0f;
            float b = (k0 + 1 < J1 && m < J2) ? W2[(k0 + 1) * J2 + m] : 0.0f;
            W2F[idx] = pack2(a, b);
        }
    } else {
        if (tid < 48) {
            b2p[tid] = (tid < J2) ? b2[tid] : 0.0f;
            W3p[tid] = (tid < J2) ? W3[tid] : 0.0f;
        }
    }
}

// ---- fused: TWO waves per bn (tiles 0..6 / 7..12); 512-thr block = 4 bn.
// Weights in LDS (staged once/block). 4096 waves, 2 blocks/CU, 66KB LDS ->
// ALL waves resident (4/SIMD) — doubles R14's latency hiding. Tile body
// verified R12/R14; sigmoid now via v_rcp (div expansion was ~45% of VALU).
__global__ __launch_bounds__(512, 4) void attn_w2(
        const float* __restrict__ queries, const float* __restrict__ keys,
        const int*   __restrict__ keys_length,
        const float* __restrict__ QW,
        const bf16x8* __restrict__ kbf0, const bf16x8* __restrict__ kbf1,
        const bf16x8* __restrict__ WALL,   // WBF(20) ++ W2F(9) frags
        const float* __restrict__ b2p, const float* __restrict__ W3p,
        const float* __restrict__ b3,
        float* __restrict__ out) {
    const int tid  = threadIdx.x;
    const int lane = tid & 63, wv = tid >> 6;            // 8 waves
    const int blk  = (blockIdx.x & 7) * 64 + (blockIdx.x >> 3);  // 512 = 8*64
    const int bnL  = wv >> 1;                            // 0..3 in block
    const int half = wv & 1;                             // tile range half
    const int bn   = blk * 4 + bnL;
    const int b    = bn >> 4;
    const int cl   = lane & 15, rg = lane >> 4;

    __shared__ __align__(16) short wlds[29 * 64 * 8];    // 29,696 B
    __shared__ __align__(16) short X1[8][16][108];       // 27,648 B (R12: 0 conflicts)
    __shared__ float z3s[4][208];                        //  3,328 B
    __shared__ float wsm[4][208];                        //  3,328 B
    __shared__ float part[8][64];                        //  2,048 B  (66,048 total)

    // ---- stage ALL weights to LDS once ----
    for (int i = tid; i < 29 * 64; i += 512)
        ((bf16x8*)wlds)[i] = WALL[i];
    // zero own-wave X1 k-pad cols 80..95
    #pragma unroll
    for (int i = 0; i < 4; ++i)
        X1[wv][rg + 4 * i][80 + cl] = 0;
    __syncthreads();

    const bf16x8* wl = (const bf16x8*)wlds;              // [0,20)=WBF, [20,29)=W2F

    // ---- hoisted per-bn constants ----
    const float* qp = queries + bn * H_;
    float4 qa = *(const float4*)(qp + 8 * rg);
    float4 qb = *(const float4*)(qp + 8 * rg + 4);
    float4 qc = *(const float4*)(qp + 32 + 8 * rg);
    float4 qd = *(const float4*)(qp + 36 + 8 * rg);
    float4 qw4[5];
    #pragma unroll
    for (int nt = 0; nt < 5; ++nt)
        qw4[nt] = *(const float4*)(QW + bn * J1 + 16 * nt + 4 * rg);
    float4 b24[3], w34[3];
    #pragma unroll
    for (int nt = 0; nt < 3; ++nt) {
        b24[nt] = *(const float4*)(b2p + 16 * nt + 4 * rg);
        w34[nt] = *(const float4*)(W3p + 16 * nt + 4 * rg);
    }
    const float b3v = b3[0];
    const float* kb = keys + (size_t)b * T_ * H_;

    // ---- tile loop: half 0 -> mt 0..6, half 1 -> mt 7..12 ----
    const int mt0 = half * 7;
    const int mtE = half ? NTILE : 7;
    bf16x8 nk0 = kbf0[(b * NTILE + mt0) * 64 + lane];    // prefetch first tile
    bf16x8 nk1 = kbf1[(b * NTILE + mt0) * 64 + lane];
    #pragma unroll 1
    for (int mt = mt0; mt < mtE; ++mt) {
        bf16x8 k0 = nk0, k1 = nk1;
        {   // prefetch next (clamped; named regs)
            int mn = mt + 1 < mtE ? mt + 1 : mtE - 1;
            nk0 = kbf0[(b * NTILE + mn) * 64 + lane];
            nk1 = kbf1[(b * NTILE + mn) * 64 + lane];
        }
        const uint4 kw0 = *(const uint4*)&k0;
        const uint4 kw1 = *(const uint4*)&k1;
        uint4 kqw0, kqw1;
        kqw0.x = kqword(kw0.x, qa.x, qa.y);
        kqw0.y = kqword(kw0.y, qa.z, qa.w);
        kqw0.z = kqword(kw0.z, qb.x, qb.y);
        kqw0.w = kqword(kw0.w, qb.z, qb.w);
        kqw1.x = kqword(kw1.x, qc.x, qc.y);
        kqw1.y = kqword(kw1.y, qc.z, qc.w);
        kqw1.z = kqword(kw1.z, qd.x, qd.y);
        kqw1.w = kqword(kw1.w, qd.z, qd.w);
        bf16x8 kq0 = *(bf16x8*)&kqw0;
        bf16x8 kq1 = *(bf16x8*)&kqw1;

        // layer 1 (swapped): acc[nt] = Z1^T rows j=16nt+4rg+i, col t=cl
        f32x4 acc[5];
        #pragma unroll
        for (int nt = 0; nt < 5; ++nt) {
            acc[nt][0] = qw4[nt].x; acc[nt][1] = qw4[nt].y;
            acc[nt][2] = qw4[nt].z; acc[nt][3] = qw4[nt].w;
        }
        #pragma unroll
        for (int nt = 0; nt < 5; ++nt) {
            acc[nt] = __builtin_amdgcn_mfma_f32_16x16x32_bf16(wl[( 0 + nt) * 64 + lane], kq0, acc[nt], 0, 0, 0);
            acc[nt] = __builtin_amdgcn_mfma_f32_16x16x32_bf16(wl[( 5 + nt) * 64 + lane], kq1, acc[nt], 0, 0, 0);
            acc[nt] = __builtin_amdgcn_mfma_f32_16x16x32_bf16(wl[(10 + nt) * 64 + lane], k0,  acc[nt], 0, 0, 0);
            acc[nt] = __builtin_amdgcn_mfma_f32_16x16x32_bf16(wl[(15 + nt) * 64 + lane], k1,  acc[nt], 0, 0, 0);
        }

        // sigmoid -> X1[t=cl][j]: 2 cvt_pk + 1 b64 write per nt
        #pragma unroll
        for (int nt = 0; nt < 5; ++nt) {
            unsigned r0 = cvtpk(sigmoidf_(acc[nt][0]), sigmoidf_(acc[nt][1]));
            unsigned r1 = cvtpk(sigmoidf_(acc[nt][2]), sigmoidf_(acc[nt][3]));
            *(uint2*)&X1[wv][cl][16 * nt + 4 * rg] = make_uint2(r0, r1);
        }

        // layer 2 (swapped): acc2[nt] = Z2^T rows m=16nt+4rg+i, col t=cl
        f32x4 acc2[3];
        #pragma unroll
        for (int nt = 0; nt < 3; ++nt) {
            acc2[nt][0] = b24[nt].x; acc2[nt][1] = b24[nt].y;
            acc2[nt][2] = b24[nt].z; acc2[nt][3] = b24[nt].w;
        }
        #pragma unroll
        for (int ks = 0; ks < 3; ++ks) {
            bf16x8 xa = *(const bf16x8*)&X1[wv][cl][8 * rg + 32 * ks];
            acc2[0] = __builtin_amdgcn_mfma_f32_16x16x32_bf16(wl[(20 + 0 + ks) * 64 + lane], xa, acc2[0], 0, 0, 0);
            acc2[1] = __builtin_amdgcn_mfma_f32_16x16x32_bf16(wl[(20 + 3 + ks) * 64 + lane], xa, acc2[1], 0, 0, 0);
            acc2[2] = __builtin_amdgcn_mfma_f32_16x16x32_bf16(wl[(20 + 6 + ks) * 64 + lane], xa, acc2[2], 0, 0, 0);
        }

        // layer 3: lane owns t=cl; 12 fma then 2 shfl over rg
        float p = 0.f;
        #pragma unroll
        for (int nt = 0; nt < 3; ++nt) {
            p = fmaf(sigmoidf_(acc2[nt][0]), w34[nt].x, p);
            p = fmaf(sigmoidf_(acc2[nt][1]), w34[nt].y, p);
            p = fmaf(sigmoidf_(acc2[nt][2]), w34[nt].z, p);
            p = fmaf(sigmoidf_(acc2[nt][3]), w34[nt].w, p);
        }
        p += __shfl_xor(p, 16);
        p += __shfl_xor(p, 32);
        if (rg == 0) z3s[bnL][mt * 16 + cl] = p + b3v;
    }
    __syncthreads();

    // ---- in-wave softmax (both waves of the pair: identical values) ----
    const int L  = keys_length[b];
    const int t0 = lane, t1 = lane + 64, t2 = lane + 128, t3 = lane + 192;
    float r0 = z3s[bnL][t0], r1 = z3s[bnL][t1], r2 = z3s[bnL][t2];
    float r3 = (t3 < 208) ? z3s[bnL][t3] : 0.0f;
    float s0 = (t0 < L) ? r0 * 0.125f : NEGV * 0.125f;
    float s1 = (t1 < L) ? r1 * 0.125f : NEGV * 0.125f;
    float s2 = (t2 < L) ? r2 * 0.125f : NEGV * 0.125f;
    float s3 = (t3 < T_ && t3 < L) ? r3 * 0.125f : ((t3 < T_) ? NEGV * 0.125f : -3.0e38f);

    float mx = fmaxf(fmaxf(s0, s1), fmaxf(s2, s3));
    #pragma unroll
    for (int off = 32; off > 0; off >>= 1) mx = fmaxf(mx, __shfl_xor(mx, off));

    float e0 = __expf(s0 - mx);
    float e1 = __expf(s1 - mx);
    float e2 = __expf(s2 - mx);
    float e3 = (t3 < T_) ? __expf(s3 - mx) : 0.0f;
    float sm = e0 + e1 + e2 + e3;
    #pragma unroll
    for (int off = 32; off > 0; off >>= 1) sm += __shfl_xor(sm, off);

    float inv = __builtin_amdgcn_rcpf(sm);
    wsm[bnL][t0] = e0 * inv;                 // both pair-waves write identical bits
    wsm[bnL][t1] = e1 * inv;
    wsm[bnL][t2] = e2 * inv;
    if (t3 < T_) wsm[bnL][t3] = e3 * inv;
    __syncthreads();

    // ---- PV: wave covers t in [100*half, 100*half+100); h = lane ----
    float acc_ = 0.f;
    {
        int tb = 100 * half;
        #pragma unroll 10
        for (int t = tb; t < tb + 100; ++t)
            acc_ = fmaf(wsm[bnL][t], kb[(size_t)t * H_ + lane], acc_);
    }
    part[wv][lane] = acc_;
    __syncthreads();
    if (half == 0)
        out[bn * H_ + lane] = part[wv][lane] + part[wv + 1][lane];
}

// --- fallback (no workspace): round-3 verified pure-VALU kernel ----------
__global__ __launch_bounds__(256, 3) void attn_nows(
        const float* __restrict__ queries, const float* __restrict__ keys,
        const int*   __restrict__ keys_length,
        const float* __restrict__ W1, const float* __restrict__ b1,
        const float* __restrict__ W2, const float* __restrict__ b2,
        const float* __restrict__ W3, const float* __restrict__ b3,
        float* __restrict__ out) {
    const int tid = threadIdx.x;
    const int bn = (blockIdx.x & 7) * 256 + (blockIdx.x >> 3);
    const int b  = bn >> 4;

    __shared__ float kT[H_][T_ + 1];
    __shared__ float wsm[T_];
    __shared__ float part[256];
    __shared__ float red[8];
    __shared__ float QWq[J1];

    for (int idx = tid; idx < T_ * H_; idx += 256) {
        int t = idx >> 6, h = idx & 63;
        kT[h][t] = keys[(b * T_ + t) * H_ + h];
    }
    if (tid < J1) {
        float acc = b1[tid];
        const float* qp = queries + bn * H_;
        for (int h = 0; h < H_; ++h)
            acc = fmaf(qp[h], W1[h * J1 + tid] + W1[(128 + h) * J1 + tid], acc);
        QWq[tid] = acc;
    }
    __syncthreads();

    const int tt = (tid < T_) ? tid : 0;
    const float* qp = queries + bn * H_;

    float qk[H_];
    #pragma unroll
    for (int h = 0; h < H_; ++h) qk[h] = qp[h] * kT[h][tt];

    float z2[J2];
    #pragma unroll
    for (int m = 0; m < J2; ++m) z2[m] = b2[m];

    #pragma unroll 1
    for (int c = 0; c < 4; ++c) {
        const int j0 = c * 20;
        float z1c[20];
        #pragma unroll
        for (int j = 0; j < 20; ++j) z1c[j] = QWq[j0 + j];
        #pragma unroll
        for (int h = 0; h < H_; ++h) {
            float kh = kT[h][tt];
            const float* Wd = W1 + (192 + h) * J1 + j0;
            const float* Wb = W1 + (64 + h) * J1 + j0;
            const float* Wc = W1 + (128 + h) * J1 + j0;
            #pragma unroll
            for (int j = 0; j < 20; ++j)
                z1c[j] = fmaf(qk[h], Wd[j], fmaf(kh, Wb[j] - Wc[j], z1c[j]));
        }
        #pragma unroll
        for (int j = 0; j < 20; ++j) {
            float x = sigmoidf_(z1c[j]);
            const float* w2 = W2 + (j0 + j) * J2;
            #pragma unroll
            for (int m = 0; m < J2; ++m) z2[m] = fmaf(x, w2[m], z2[m]);
        }
    }

    float z3 = b3[0];
    #pragma unroll
    for (int m = 0; m < J2; ++m) z3 = fmaf(sigmoidf_(z2[m]), W3[m], z3);

    const int L = keys_length[b];
    float s = (tid < T_) ? ((tid < L) ? z3 : NEGV) * 0.125f : -3.0e38f;

    float mx = s;
    #pragma unroll
    for (int off = 32; off > 0; off >>= 1) mx = fmaxf(mx, __shfl_xor(mx, off));
    if ((tid & 63) == 0) red[tid >> 6] = mx;
    __syncthreads();
    mx = fmaxf(fmaxf(red[0], red[1]), fmaxf(red[2], red[3]));

    float e = (tid < T_) ? __expf(s - mx) : 0.0f;
    float sm = e;
    #pragma unroll
    for (int off = 32; off > 0; off >>= 1) sm += __shfl_xor(sm, off);
    __syncthreads();
    if ((tid & 63) == 0) red[4 + (tid >> 6)] = sm;
    __syncthreads();
    sm = red[4] + red[5] + red[6] + red[7];

    if (tid < T_) wsm[tid] = e / sm;
    __syncthreads();

    {
        int h = tid & 63, p = tid >> 6;
        float acc = 0.f;
        int t0 = p * 50;
        for (int t = t0; t < t0 + 50; ++t)
            acc = fmaf(wsm[t], kT[h][t], acc);
        part[tid] = acc;
    }
    __syncthreads();
    if (tid < 64) {
        out[bn * H_ + tid] = part[tid] + part[64 + tid] + part[128 + tid] + part[192 + tid];
    }
}

extern "C" void kernel_launch(void* const* d_in, const int* in_sizes, int n_in,
                              void* d_out, int out_size, void* d_ws, size_t ws_size,
                              hipStream_t stream) {
    const float* queries = (const float*)d_in[0];
    const float* keys    = (const float*)d_in[1];
    const int*   klen    = (const int*)  d_in[2];
    const float* W1 = (const float*)d_in[3];
    const float* b1 = (const float*)d_in[4];
    const float* W2 = (const float*)d_in[5];
    const float* b2 = (const float*)d_in[6];
    const float* W3 = (const float*)d_in[7];
    const float* b3 = (const float*)d_in[8];
    float* out = (float*)d_out;

    // ws layout (16B multiples; WBF and W2F CONTIGUOUS for single coop copy):
    // QW   [2048*80 f32]   =   655,360 B
    // kbf0 [106496 x 16B]  = 1,703,936 B
    // kbf1 [106496 x 16B]  = 1,703,936 B
    // WBF  [20*64 x 16B]   =    20,480 B   <- WALL starts here
    // W2F  [2304 u32]      =     9,216 B   <- contiguous after WBF
    // b2p/W3p [64 f32 each]=       512 B
    const size_t nkbf = (size_t)B_ * NTILE * 64;
    const size_t need = 655360 + 2 * 1703936 + 20480 + 9216 + 512;

    if (ws_size >= need) {
        char* base = (char*)d_ws;
        float*  QW   = (float*)base;
        bf16x8* kbf0 = (bf16x8*)(base + 655360);
        bf16x8* kbf1 = kbf0 + nkbf;
        bf16x8* WBF  = kbf1 + nkbf;
        unsigned* W2F = (unsigned*)((char*)WBF + 20480);
        float*  b2p  = (float*)((char*)W2F + 9216);
        float*  W3p  = b2p + 64;

        prep<<<dim3(P_QW + P_WB + P_KB + P_W2 + P_PB), dim3(256), 0, stream>>>(
            queries, keys, W1, b1, W2, b2, W3,
            QW, (unsigned*)WBF, kbf0, kbf1, W2F, b2p, W3p);
        attn_w2<<<dim3(512), dim3(512), 0, stream>>>(
            queries, keys, klen, QW, kbf0, kbf1, WBF, b2p, W3p, b3, out);
    } else {
        attn_nows<<<dim3(B_ * N_), dim3(256), 0, stream>>>(
            queries, keys, klen, W1, b1, W2, b2, W3, b3, out);
    }
}

// Round 20
// 39.705 us; speedup vs baseline: 1.6202x; 1.0005x over previous
//
#include <hip/hip_runtime.h>
#include <hip/hip_bf16.h>
#include <math.h>

#define B_  128
#define N_  16
#define T_  200
#define H_  64
#define J1  80
#define J2  40
#define NTILE 13
#define NEGV -4294967295.0f   // -2^32 + 1

typedef __attribute__((ext_vector_type(8))) short bf16x8;
typedef __attribute__((ext_vector_type(4))) float f32x4;

// fast sigmoid: v_rcp_f32 (1 ulp) instead of the ~10-op f32 div expansion
__device__ __forceinline__ float sigmoidf_(float x) {
    return __builtin_amdgcn_rcpf(1.0f + __expf(-x));
}
// branch-free RNE f32->bf16 (finite inputs only)
__device__ __forceinline__ short f2b(float x) {
    unsigned u = __float_as_uint(x);
    return (short)((u + 0x7FFF + ((u >> 16) & 1)) >> 16);
}
__device__ __forceinline__ unsigned pack2(float a, float b) {
    return (unsigned)(unsigned short)f2b(a) | ((unsigned)(unsigned short)f2b(b) << 16);
}
// HW packed convert: dst = {lo16: bf16(a), hi16: bf16(b)}
__device__ __forceinline__ unsigned cvtpk(float a, float b) {
    unsigned r;
    asm("v_cvt_pk_bf16_f32 %0, %1, %2" : "=v"(r) : "v"(a), "v"(b));
    return r;
}
// kq word: in-register bf16 extract + mul + cvt_pk = 5 VALU
__device__ __forceinline__ unsigned kqword(unsigned w, float ql, float qh) {
    float lo = __uint_as_float(w << 16) * ql;
    float hi = __uint_as_float(w & 0xffff0000u) * qh;
    return cvtpk(lo, hi);
}

// ---- prep: ONE dispatch, 5 ranges (verified R12-R15) ---------------------
#define P_QW 160
#define P_WB 20
#define P_KB 416
#define P_W2 9
#define P_PB 1
__global__ void prep(const float* __restrict__ queries,
                     const float* __restrict__ keys,
                     const float* __restrict__ W1,
                     const float* __restrict__ b1,
                     const float* __restrict__ W2,
                     const float* __restrict__ b2,
                     const float* __restrict__ W3,
                     float* __restrict__ QW,
                     unsigned* __restrict__ WBFu,
                     bf16x8* __restrict__ kbf0, bf16x8* __restrict__ kbf1,
                     unsigned* __restrict__ W2F,
                     float* __restrict__ b2p, float* __restrict__ W3p) {
    const int blk = blockIdx.x, tid = threadIdx.x;
    if (blk < P_QW) {
        int idx = blk * 256 + tid;                 // (bn, j/4), exact
        int bn = idx / 20, j = (idx % 20) * 4;
        float4 acc = *(const float4*)(b1 + j);
        const float* qp = queries + bn * H_;
        for (int h = 0; h < H_; ++h) {
            float qh = qp[h];
            float4 wa = *(const float4*)(W1 + h * J1 + j);
            float4 wc = *(const float4*)(W1 + (128 + h) * J1 + j);
            acc.x = fmaf(qh, wa.x + wc.x, acc.x);
            acc.y = fmaf(qh, wa.y + wc.y, acc.y);
            acc.z = fmaf(qh, wa.z + wc.z, acc.z);
            acc.w = fmaf(qh, wa.w + wc.w, acc.w);
        }
        *(float4*)(QW + bn * J1 + j) = acc;
    } else if (blk < P_QW + P_WB) {
        int idx = (blk - P_QW) * 256 + tid;        // = fi*256 + l*4 + rp, exact
        int rp = idx & 3, l = (idx >> 2) & 63, fi = idx >> 8;
        int j  = (fi % 5) * 16 + (l & 15);
        int R  = (fi / 5) * 32 + 8 * (l >> 4) + 2 * rp;
        float a, b;
        if (R < 64) {
            a = W1[(192 + R) * J1 + j];
            b = W1[(193 + R) * J1 + j];
        } else {
            int r2 = R - 64;
            a = W1[(64 + r2) * J1 + j] - W1[(128 + r2) * J1 + j];
            b = W1[(65 + r2) * J1 + j] - W1[(129 + r2) * J1 + j];
        }
        WBFu[idx] = pack2(a, b);
    } else if (blk < P_QW + P_WB + P_KB) {
        int idx = (blk - P_QW - P_WB) * 256 + tid; // (b*13+mt)*64+l, exact
        int l  = idx & 63, bm = idx >> 6;
        int mt = bm % NTILE, b = bm / NTILE;
        int t  = mt * 16 + (l & 15); if (t > T_ - 1) t = T_ - 1;
        int rg = l >> 4;
        const float* kr = keys + ((size_t)(b * T_ + t)) * H_ + 8 * rg;
        float4 a0 = *(const float4*)(kr);
        float4 a1 = *(const float4*)(kr + 4);
        float4 a2 = *(const float4*)(kr + 32);
        float4 a3 = *(const float4*)(kr + 36);
        bf16x8 f0, f1;
        f0[0] = f2b(a0.x); f0[1] = f2b(a0.y); f0[2] = f2b(a0.z); f0[3] = f2b(a0.w);
        f0[4] = f2b(a1.x); f0[5] = f2b(a1.y); f0[6] = f2b(a1.z); f0[7] = f2b(a1.w);
        f1[0] = f2b(a2.x); f1[1] = f2b(a2.y); f1[2] = f2b(a2.z); f1[3] = f2b(a2.w);
        f1[4] = f2b(a3.x); f1[5] = f2b(a3.y); f1[6] = f2b(a3.z); f1[7] = f2b(a3.w);
        kbf0[idx] = f0; kbf1[idx] = f1;
    } else if (blk < P_QW + P_WB + P_KB + P_W2) {
        int idx = (blk - P_QW - P_WB - P_KB) * 256 + tid;
        if (idx < 9 * 64 * 4) {
            int rp = idx & 3;
            int l  = (idx >> 2) & 63;
            int f  = idx >> 8;
            int m  = (f / 3) * 16 + (l & 15);
            int k0 = (f % 3) * 32 + 8 * (l >> 4) + 2 * rp;
            float a = (k0     < J1 && m < J2) ? W2[k0 * J2 + m]       : 0.0f;
            float b = (k0 + 1 < J1 && m < J2) ? W2[(k0 + 1) * J2 + m] : 0.0f;
            W2F[idx] = pack2(a, b);
        }
    } else {
        if (tid < 48) {
            b2p[tid] = (tid < J2) ? b2[tid] : 0.0f;
            W3p[tid] = (tid < J2) ? W3[tid] : 0.0f;
        }
    }
}

// ---- fused: TWO waves per bn (tiles 0..6 / 7..12); 512-thr block = 4 bn.
// Weights in LDS (staged once/block). 4096 waves, 2 blocks/CU, 66KB LDS ->
// ALL waves resident (4/SIMD). Tile body verified R12/R14/R15; sigmoid via
// v_rcp. R15-verified kernel, restored after the R16-R18 bundle failed.
__global__ __launch_bounds__(512, 4) void attn_w2(
        const float* __restrict__ queries, const float* __restrict__ keys,
        const int*   __restrict__ keys_length,
        const float* __restrict__ QW,
        const bf16x8* __restrict__ kbf0, const bf16x8* __restrict__ kbf1,
        const bf16x8* __restrict__ WALL,   // WBF(20) ++ W2F(9) frags
        const float* __restrict__ b2p, const float* __restrict__ W3p,
        const float* __restrict__ b3,
        float* __restrict__ out) {
    const int tid  = threadIdx.x;
    const int lane = tid & 63, wv = tid >> 6;            // 8 waves
    const int blk  = (blockIdx.x & 7) * 64 + (blockIdx.x >> 3);  // 512 = 8*64
    const int bnL  = wv >> 1;                            // 0..3 in block
    const int half = wv & 1;                             // tile range half
    const int bn   = blk * 4 + bnL;
    const int b    = bn >> 4;
    const int cl   = lane & 15, rg = lane >> 4;

    __shared__ __align__(16) short wlds[29 * 64 * 8];    // 29,696 B
    __shared__ __align__(16) short X1[8][16][108];       // 27,648 B (R12: 0 conflicts)
    __shared__ float z3s[4][208];                        //  3,328 B
    __shared__ float wsm[4][208];                        //  3,328 B
    __shared__ float part[8][64];                        //  2,048 B  (66,048 total)

    // ---- stage ALL weights to LDS once ----
    for (int i = tid; i < 29 * 64; i += 512)
        ((bf16x8*)wlds)[i] = WALL[i];
    // zero own-wave X1 k-pad cols 80..95
    #pragma unroll
    for (int i = 0; i < 4; ++i)
        X1[wv][rg + 4 * i][80 + cl] = 0;
    __syncthreads();

    const bf16x8* wl = (const bf16x8*)wlds;              // [0,20)=WBF, [20,29)=W2F

    // ---- hoisted per-bn constants ----
    const float* qp = queries + bn * H_;
    float4 qa = *(const float4*)(qp + 8 * rg);
    float4 qb = *(const float4*)(qp + 8 * rg + 4);
    float4 qc = *(const float4*)(qp + 32 + 8 * rg);
    float4 qd = *(const float4*)(qp + 36 + 8 * rg);
    float4 qw4[5];
    #pragma unroll
    for (int nt = 0; nt < 5; ++nt)
        qw4[nt] = *(const float4*)(QW + bn * J1 + 16 * nt + 4 * rg);
    float4 b24[3], w34[3];
    #pragma unroll
    for (int nt = 0; nt < 3; ++nt) {
        b24[nt] = *(const float4*)(b2p + 16 * nt + 4 * rg);
        w34[nt] = *(const float4*)(W3p + 16 * nt + 4 * rg);
    }
    const float b3v = b3[0];
    const float* kb = keys + (size_t)b * T_ * H_;

    // ---- tile loop: half 0 -> mt 0..6, half 1 -> mt 7..12 ----
    const int mt0 = half * 7;
    const int mtE = half ? NTILE : 7;
    bf16x8 nk0 = kbf0[(b * NTILE + mt0) * 64 + lane];    // prefetch first tile
    bf16x8 nk1 = kbf1[(b * NTILE + mt0) * 64 + lane];
    #pragma unroll 1
    for (int mt = mt0; mt < mtE; ++mt) {
        bf16x8 k0 = nk0, k1 = nk1;
        {   // prefetch next (clamped; named regs)
            int mn = mt + 1 < mtE ? mt + 1 : mtE - 1;
            nk0 = kbf0[(b * NTILE + mn) * 64 + lane];
            nk1 = kbf1[(b * NTILE + mn) * 64 + lane];
        }
        const uint4 kw0 = *(const uint4*)&k0;
        const uint4 kw1 = *(const uint4*)&k1;
        uint4 kqw0, kqw1;
        kqw0.x = kqword(kw0.x, qa.x, qa.y);
        kqw0.y = kqword(kw0.y, qa.z, qa.w);
        kqw0.z = kqword(kw0.z, qb.x, qb.y);
        kqw0.w = kqword(kw0.w, qb.z, qb.w);
        kqw1.x = kqword(kw1.x, qc.x, qc.y);
        kqw1.y = kqword(kw1.y, qc.z, qc.w);
        kqw1.z = kqword(kw1.z, qd.x, qd.y);
        kqw1.w = kqword(kw1.w, qd.z, qd.w);
        bf16x8 kq0 = *(bf16x8*)&kqw0;
        bf16x8 kq1 = *(bf16x8*)&kqw1;

        // layer 1 (swapped): acc[nt] = Z1^T rows j=16nt+4rg+i, col t=cl
        f32x4 acc[5];
        #pragma unroll
        for (int nt = 0; nt < 5; ++nt) {
            acc[nt][0] = qw4[nt].x; acc[nt][1] = qw4[nt].y;
            acc[nt][2] = qw4[nt].z; acc[nt][3] = qw4[nt].w;
        }
        #pragma unroll
        for (int nt = 0; nt < 5; ++nt) {
            acc[nt] = __builtin_amdgcn_mfma_f32_16x16x32_bf16(wl[( 0 + nt) * 64 + lane], kq0, acc[nt], 0, 0, 0);
            acc[nt] = __builtin_amdgcn_mfma_f32_16x16x32_bf16(wl[( 5 + nt) * 64 + lane], kq1, acc[nt], 0, 0, 0);
            acc[nt] = __builtin_amdgcn_mfma_f32_16x16x32_bf16(wl[(10 + nt) * 64 + lane], k0,  acc[nt], 0, 0, 0);
            acc[nt] = __builtin_amdgcn_mfma_f32_16x16x32_bf16(wl[(15 + nt) * 64 + lane], k1,  acc[nt], 0, 0, 0);
        }

        // sigmoid -> X1[t=cl][j]: 2 cvt_pk + 1 b64 write per nt
        #pragma unroll
        for (int nt = 0; nt < 5; ++nt) {
            unsigned r0 = cvtpk(sigmoidf_(acc[nt][0]), sigmoidf_(acc[nt][1]));
            unsigned r1 = cvtpk(sigmoidf_(acc[nt][2]), sigmoidf_(acc[nt][3]));
            *(uint2*)&X1[wv][cl][16 * nt + 4 * rg] = make_uint2(r0, r1);
        }

        // layer 2 (swapped): acc2[nt] = Z2^T rows m=16nt+4rg+i, col t=cl
        f32x4 acc2[3];
        #pragma unroll
        for (int nt = 0; nt < 3; ++nt) {
            acc2[nt][0] = b24[nt].x; acc2[nt][1] = b24[nt].y;
            acc2[nt][2] = b24[nt].z; acc2[nt][3] = b24[nt].w;
        }
        #pragma unroll
        for (int ks = 0; ks < 3; ++ks) {
            bf16x8 xa = *(const bf16x8*)&X1[wv][cl][8 * rg + 32 * ks];
            acc2[0] = __builtin_amdgcn_mfma_f32_16x16x32_bf16(wl[(20 + 0 + ks) * 64 + lane], xa, acc2[0], 0, 0, 0);
            acc2[1] = __builtin_amdgcn_mfma_f32_16x16x32_bf16(wl[(20 + 3 + ks) * 64 + lane], xa, acc2[1], 0, 0, 0);
            acc2[2] = __builtin_amdgcn_mfma_f32_16x16x32_bf16(wl[(20 + 6 + ks) * 64 + lane], xa, acc2[2], 0, 0, 0);
        }

        // layer 3: lane owns t=cl; 12 fma then 2 shfl over rg
        float p = 0.f;
        #pragma unroll
        for (int nt = 0; nt < 3; ++nt) {
            p = fmaf(sigmoidf_(acc2[nt][0]), w34[nt].x, p);
            p = fmaf(sigmoidf_(acc2[nt][1]), w34[nt].y, p);
            p = fmaf(sigmoidf_(acc2[nt][2]), w34[nt].z, p);
            p = fmaf(sigmoidf_(acc2[nt][3]), w34[nt].w, p);
        }
        p += __shfl_xor(p, 16);
        p += __shfl_xor(p, 32);
        if (rg == 0) z3s[bnL][mt * 16 + cl] = p + b3v;
    }
    __syncthreads();

    // ---- in-wave softmax (both waves of the pair: identical values) ----
    const int L  = keys_length[b];
    const int t0 = lane, t1 = lane + 64, t2 = lane + 128, t3 = lane + 192;
    float r0 = z3s[bnL][t0], r1 = z3s[bnL][t1], r2 = z3s[bnL][t2];
    float r3 = (t3 < 208) ? z3s[bnL][t3] : 0.0f;
    float s0 = (t0 < L) ? r0 * 0.125f : NEGV * 0.125f;
    float s1 = (t1 < L) ? r1 * 0.125f : NEGV * 0.125f;
    float s2 = (t2 < L) ? r2 * 0.125f : NEGV * 0.125f;
    float s3 = (t3 < T_ && t3 < L) ? r3 * 0.125f : ((t3 < T_) ? NEGV * 0.125f : -3.0e38f);

    float mx = fmaxf(fmaxf(s0, s1), fmaxf(s2, s3));
    #pragma unroll
    for (int off = 32; off > 0; off >>= 1) mx = fmaxf(mx, __shfl_xor(mx, off));

    float e0 = __expf(s0 - mx);
    float e1 = __expf(s1 - mx);
    float e2 = __expf(s2 - mx);
    float e3 = (t3 < T_) ? __expf(s3 - mx) : 0.0f;
    float sm = e0 + e1 + e2 + e3;
    #pragma unroll
    for (int off = 32; off > 0; off >>= 1) sm += __shfl_xor(sm, off);

    float inv = __builtin_amdgcn_rcpf(sm);
    wsm[bnL][t0] = e0 * inv;                 // both pair-waves write identical bits
    wsm[bnL][t1] = e1 * inv;
    wsm[bnL][t2] = e2 * inv;
    if (t3 < T_) wsm[bnL][t3] = e3 * inv;
    __syncthreads();

    // ---- PV: wave covers t in [100*half, 100*half+100); h = lane ----
    float acc_ = 0.f;
    {
        int tb = 100 * half;
        #pragma unroll 10
        for (int t = tb; t < tb + 100; ++t)
            acc_ = fmaf(wsm[bnL][t], kb[(size_t)t * H_ + lane], acc_);
    }
    part[wv][lane] = acc_;
    __syncthreads();
    if (half == 0)
        out[bn * H_ + lane] = part[wv][lane] + part[wv + 1][lane];
}

// --- fallback (no workspace): round-3 verified pure-VALU kernel ----------
__global__ __launch_bounds__(256, 3) void attn_nows(
        const float* __restrict__ queries, const float* __restrict__ keys,
        const int*   __restrict__ keys_length,
        const float* __restrict__ W1, const float* __restrict__ b1,
        const float* __restrict__ W2, const float* __restrict__ b2,
        const float* __restrict__ W3, const float* __restrict__ b3,
        float* __restrict__ out) {
    const int tid = threadIdx.x;
    const int bn = (blockIdx.x & 7) * 256 + (blockIdx.x >> 3);
    const int b  = bn >> 4;

    __shared__ float kT[H_][T_ + 1];
    __shared__ float wsm[T_];
    __shared__ float part[256];
    __shared__ float red[8];
    __shared__ float QWq[J1];

    for (int idx = tid; idx < T_ * H_; idx += 256) {
        int t = idx >> 6, h = idx & 63;
        kT[h][t] = keys[(b * T_ + t) * H_ + h];
    }
    if (tid < J1) {
        float acc = b1[tid];
        const float* qp = queries + bn * H_;
        for (int h = 0; h < H_; ++h)
            acc = fmaf(qp[h], W1[h * J1 + tid] + W1[(128 + h) * J1 + tid], acc);
        QWq[tid] = acc;
    }
    __syncthreads();

    const int tt = (tid < T_) ? tid : 0;
    const float* qp = queries + bn * H_;

    float qk[H_];
    #pragma unroll
    for (int h = 0; h < H_; ++h) qk[h] = qp[h] * kT[h][tt];

    float z2[J2];
    #pragma unroll
    for (int m = 0; m < J2; ++m) z2[m] = b2[m];

    #pragma unroll 1
    for (int c = 0; c < 4; ++c) {
        const int j0 = c * 20;
        float z1c[20];
        #pragma unroll
        for (int j = 0; j < 20; ++j) z1c[j] = QWq[j0 + j];
        #pragma unroll
        for (int h = 0; h < H_; ++h) {
            float kh = kT[h][tt];
            const float* Wd = W1 + (192 + h) * J1 + j0;
            const float* Wb = W1 + (64 + h) * J1 + j0;
            const float* Wc = W1 + (128 + h) * J1 + j0;
            #pragma unroll
            for (int j = 0; j < 20; ++j)
                z1c[j] = fmaf(qk[h], Wd[j], fmaf(kh, Wb[j] - Wc[j], z1c[j]));
        }
        #pragma unroll
        for (int j = 0; j < 20; ++j) {
            float x = sigmoidf_(z1c[j]);
            const float* w2 = W2 + (j0 + j) * J2;
            #pragma unroll
            for (int m = 0; m < J2; ++m) z2[m] = fmaf(x, w2[m], z2[m]);
        }
    }

    float z3 = b3[0];
    #pragma unroll
    for (int m = 0; m < J2; ++m) z3 = fmaf(sigmoidf_(z2[m]), W3[m], z3);

    const int L = keys_length[b];
    float s = (tid < T_) ? ((tid < L) ? z3 : NEGV) * 0.125f : -3.0e38f;

    float mx = s;
    #pragma unroll
    for (int off = 32; off > 0; off >>= 1) mx = fmaxf(mx, __shfl_xor(mx, off));
    if ((tid & 63) == 0) red[tid >> 6] = mx;
    __syncthreads();
    mx = fmaxf(fmaxf(red[0], red[1]), fmaxf(red[2], red[3]));

    float e = (tid < T_) ? __expf(s - mx) : 0.0f;
    float sm = e;
    #pragma unroll
    for (int off = 32; off > 0; off >>= 1) sm += __shfl_xor(sm, off);
    __syncthreads();
    if ((tid & 63) == 0) red[4 + (tid >> 6)] = sm;
    __syncthreads();
    sm = red[4] + red[5] + red[6] + red[7];

    if (tid < T_) wsm[tid] = e / sm;
    __syncthreads();

    {
        int h = tid & 63, p = tid >> 6;
        float acc = 0.f;
        int t0 = p * 50;
        for (int t = t0; t < t0 + 50; ++t)
            acc = fmaf(wsm[t], kT[h][t], acc);
        part[tid] = acc;
    }
    __syncthreads();
    if (tid < 64) {
        out[bn * H_ + tid] = part[tid] + part[64 + tid] + part[128 + tid] + part[192 + tid];
    }
}

extern "C" void kernel_launch(void* const* d_in, const int* in_sizes, int n_in,
                              void* d_out, int out_size, void* d_ws, size_t ws_size,
                              hipStream_t stream) {
    const float* queries = (const float*)d_in[0];
    const float* keys    = (const float*)d_in[1];
    const int*   klen    = (const int*)  d_in[2];
    const float* W1 = (const float*)d_in[3];
    const float* b1 = (const float*)d_in[4];
    const float* W2 = (const float*)d_in[5];
    const float* b2 = (const float*)d_in[6];
    const float* W3 = (const float*)d_in[7];
    const float* b3 = (const float*)d_in[8];
    float* out = (float*)d_out;

    // ws layout (16B multiples; WBF and W2F CONTIGUOUS for single coop copy):
    // QW   [2048*80 f32]   =   655,360 B
    // kbf0 [106496 x 16B]  = 1,703,936 B
    // kbf1 [106496 x 16B]  = 1,703,936 B
    // WBF  [20*64 x 16B]   =    20,480 B   <- WALL starts here
    // W2F  [2304 u32]      =     9,216 B   <- contiguous after WBF
    // b2p/W3p [64 f32 each]=       512 B
    const size_t nkbf = (size_t)B_ * NTILE * 64;
    const size_t need = 655360 + 2 * 1703936 + 20480 + 9216 + 512;

    if (ws_size >= need) {
        char* base = (char*)d_ws;
        float*  QW   = (float*)base;
        bf16x8* kbf0 = (bf16x8*)(base + 655360);
        bf16x8* kbf1 = kbf0 + nkbf;
        bf16x8* WBF  = kbf1 + nkbf;
        unsigned* W2F = (unsigned*)((char*)WBF + 20480);
        float*  b2p  = (float*)((char*)W2F + 9216);
        float*  W3p  = b2p + 64;

        prep<<<dim3(P_QW + P_WB + P_KB + P_W2 + P_PB), dim3(256), 0, stream>>>(
            queries, keys, W1, b1, W2, b2, W3,
            QW, (unsigned*)WBF, kbf0, kbf1, W2F, b2p, W3p);
        attn_w2<<<dim3(512), dim3(512), 0, stream>>>(
            queries, keys, klen, QW, kbf0, kbf1, WBF, b2p, W3p, b3, out);
    } else {
        attn_nows<<<dim3(B_ * N_), dim3(256), 0, stream>>>(
            queries, keys, klen, W1, b1, W2, b2, W3, b3, out);
    }
}